// Round 11
// baseline (13849.734 us; speedup 1.0000x reference)
//
#include <hip/hip_runtime.h>

typedef unsigned short ushort_t;
typedef unsigned int uint_t;
typedef float f4v __attribute__((ext_vector_type(4)));

// Problem dims: B=32 N=256 T=13 CIN=2 HID=64 EMB=10 K=2
// Output: float32, (B,N,13,HID)
// ws layout (21,823,488 B footprint):
#define CW_OFF  0          // canonical fp32 inputs (524288 B)
#define A_OFF   524288     // A  fp32 256x256
#define BN_OFF  786432     // bn fp32 256x64
#define WN_OFF  851968     // Wn bf16 flat 256x2x64x64 (4 MB)
#define XB_OFF  5046272    // XB bf16 2 x (8192x64) x-exchange double buffer
#define H_OFF   7143424    // H  fp32 8192x64
#define Z_OFF   9240576    // Z  fp32 8192x64
#define K1H_OFF 11337728
#define K1Z_OFF 13434880
#define K2H_OFF 15532032
#define K2Z_OFF 17629184
#define UH_OFF  19726336

// float-element offsets inside canonical region F
#define F_X0     0
#define F_WH     16384
#define F_BH     16512
#define F_WZ     16576
#define F_BZ     16704
#define F_WFIN   16768
#define F_BFIN   20864
#define F_WFHID  20928
#define F_BFHID  25024
#define F_WFOUT  25088
#define F_BFOUT  33280
#define F_WGIN   33408
#define F_BGIN   37504
#define F_WGOUT  37568
#define F_BGOUT  45760
#define F_EG     45888
#define F_WPOOL  48448
#define F_BPOOL  130368

__device__ __forceinline__ float bfl(uint_t u){ union{uint_t i; float f;} c; c.i = u<<16; return c.f; }
__device__ __forceinline__ float bfh(uint_t u){ union{uint_t i; float f;} c; c.i = u & 0xffff0000u; return c.f; }
__device__ __forceinline__ float bf1(ushort_t u){ union{uint_t i; float f;} c; c.i = ((uint_t)u)<<16; return c.f; }
__device__ __forceinline__ uint_t f2bf(float x){
  uint_t u = __float_as_uint(x);
  uint_t r = u + 0x7fffu + ((u >> 16) & 1u);
  return r >> 16;
}
__device__ __forceinline__ float fast_tanh(float x){
  float e = __expf(2.0f*x);
  return 1.0f - 2.0f/(e+1.0f);
}
// input dtype probe: times = arange(T). bf16 -> word0 = 0x3F800000; f32 -> 0
__device__ __forceinline__ bool inputs_are_f32(const void* times){
  return ((const uint_t*)times)[0] != 0x3F800000u;
}
__device__ __forceinline__ void ntst4(float* p, float a, float b, float c, float d){
  f4v v; v[0]=a; v[1]=b; v[2]=c; v[3]=d;
  __builtin_nontemporal_store(v, (f4v*)p);
}

// acc[0..3] += sum_i act[i] * W[i*64 + o0 + j]   (W fp32, row stride 64)
__device__ __forceinline__ void dotf_4(const float* act, const float* W, int o0, float acc[4]) {
  const float4* a4 = (const float4*)act;
  #pragma unroll
  for (int i4 = 0; i4 < 16; ++i4) {
    float4 av4 = a4[i4];
    float av[4] = {av4.x, av4.y, av4.z, av4.w};
    #pragma unroll
    for (int ii = 0; ii < 4; ++ii) {
      float4 w = *(const float4*)(W + (i4*4+ii)*64 + o0);
      acc[0] += av[ii]*w.x; acc[1] += av[ii]*w.y;
      acc[2] += av[ii]*w.z; acc[3] += av[ii]*w.w;
    }
  }
}

// acc[0..7] += sum_i act[i] * W[i*128 + co0 + j]  (W fp32, row stride 128)
__device__ __forceinline__ void dotf_8(const float* act, const float* W, int co0, float acc[8]) {
  const float4* a4 = (const float4*)act;
  #pragma unroll
  for (int i4 = 0; i4 < 16; ++i4) {
    float4 av4 = a4[i4];
    float av[4] = {av4.x, av4.y, av4.z, av4.w};
    #pragma unroll
    for (int ii = 0; ii < 4; ++ii) {
      const float* wp = W + (i4*4+ii)*128 + co0;
      float4 w0 = *(const float4*)(wp);
      float4 w1 = *(const float4*)(wp + 4);
      float a = av[ii];
      acc[0] += a*w0.x; acc[1] += a*w0.y; acc[2] += a*w0.z; acc[3] += a*w0.w;
      acc[4] += a*w1.x; acc[5] += a*w1.y; acc[6] += a*w1.z; acc[7] += a*w1.w;
    }
  }
}

__device__ __forceinline__ void cvt_copy(float* dst, const void* src, int cnt, bool f32in){
  if (f32in) {
    const float* s = (const float*)src;
    for (int i = threadIdx.x; i < cnt; i += 256) dst[i] = s[i];
  } else {
    const ushort_t* s = (const ushort_t*)src;
    for (int i = threadIdx.x; i < cnt; i += 256) dst[i] = bf1(s[i]);
  }
}

// canonicalize weights + x0 slice to fp32 in ws (bf16 OR f32 inputs)
// grid 36: bid 0..3 x0 quarters; 4..19 W_pool chunks; 20..35 small tensors
__global__ __launch_bounds__(256) void k_conv(
    const void* times, const void* ca,
    const void* W_h, const void* b_h, const void* W_z, const void* b_z,
    const void* Wf_in, const void* bf_in, const void* Wf_hid, const void* bf_hid,
    const void* Wf_out, const void* bf_out, const void* Wg_in, const void* bg_in,
    const void* Wg_out, const void* bg_out, const void* Eg, const void* W_pool,
    const void* b_pool, char* __restrict__ wsb)
{
  const bool f32in = inputs_are_f32(times);
  float* F = (float*)(wsb + CW_OFF);
  const int bid = blockIdx.x;
  if (bid < 4) {                       // x0 gather: coeff_a[..., 0, :]
    const int base = bid * 4096;
    if (f32in) {
      const float* s = (const float*)ca;
      for (int i = threadIdx.x; i < 4096; i += 256) {
        int g = base + i;
        F[F_X0 + g] = s[(g >> 1)*24 + (g & 1)];
      }
    } else {
      const ushort_t* s = (const ushort_t*)ca;
      for (int i = threadIdx.x; i < 4096; i += 256) {
        int g = base + i;
        F[F_X0 + g] = bf1(s[(g >> 1)*24 + (g & 1)]);
      }
    }
    return;
  }
  if (bid < 20) {                      // W_pool chunk
    const int off = (bid - 4) * 5120;
    const void* srcp = f32in ? (const void*)((const float*)W_pool + off)
                             : (const void*)((const ushort_t*)W_pool + off);
    cvt_copy(F + F_WPOOL + off, srcp, 5120, f32in);
    return;
  }
  const void* src = nullptr; int dst = 0, cnt = 0;
  switch (bid) {
    case 20: src = W_h;    dst = F_WH;    cnt = 128;  break;
    case 21: src = b_h;    dst = F_BH;    cnt = 64;   break;
    case 22: src = W_z;    dst = F_WZ;    cnt = 128;  break;
    case 23: src = b_z;    dst = F_BZ;    cnt = 64;   break;
    case 24: src = Wf_in;  dst = F_WFIN;  cnt = 4096; break;
    case 25: src = bf_in;  dst = F_BFIN;  cnt = 64;   break;
    case 26: src = Wf_hid; dst = F_WFHID; cnt = 4096; break;
    case 27: src = bf_hid; dst = F_BFHID; cnt = 64;   break;
    case 28: src = Wf_out; dst = F_WFOUT; cnt = 8192; break;
    case 29: src = bf_out; dst = F_BFOUT; cnt = 128;  break;
    case 30: src = Wg_in;  dst = F_WGIN;  cnt = 4096; break;
    case 31: src = bg_in;  dst = F_BGIN;  cnt = 64;   break;
    case 32: src = Wg_out; dst = F_WGOUT; cnt = 8192; break;
    case 33: src = bg_out; dst = F_BGOUT; cnt = 128;  break;
    case 34: src = Eg;     dst = F_EG;    cnt = 2560; break;
    default: src = b_pool; dst = F_BPOOL; cnt = 640;  break;
  }
  cvt_copy(F + dst, src, cnt, f32in);
}

// A = softmax(relu(Eg @ Eg^T), axis=1) ; bn = Eg @ b_pool
__global__ __launch_bounds__(256) void k_A(char* __restrict__ wsb) {
  const float* F = (const float*)(wsb + CW_OFF);
  float* Aw = (float*)(wsb + A_OFF);
  float* bn = (float*)(wsb + BN_OFF);
  const int nrow = blockIdx.x;
  const int m = threadIdx.x;
  float eg_n[10];
  #pragma unroll
  for (int d = 0; d < 10; ++d) eg_n[d] = F[F_EG + nrow*10 + d];
  float dot = 0.f;
  #pragma unroll
  for (int d = 0; d < 10; ++d) dot += eg_n[d] * F[F_EG + m*10 + d];
  float v = fmaxf(dot, 0.f);
  __shared__ float red[256];
  red[m] = v; __syncthreads();
  for (int off = 128; off > 0; off >>= 1) {
    if (m < off) red[m] = fmaxf(red[m], red[m+off]);
    __syncthreads();
  }
  float vmax = red[0]; __syncthreads();
  float e = __expf(v - vmax);
  red[m] = e; __syncthreads();
  for (int off = 128; off > 0; off >>= 1) {
    if (m < off) red[m] += red[m+off];
    __syncthreads();
  }
  float ssum = red[0];
  Aw[nrow*256 + m] = e / ssum;
  if (m < 64) {
    float acc = 0.f;
    #pragma unroll
    for (int d = 0; d < 10; ++d) acc += eg_n[d] * F[F_BPOOL + d*64 + m];
    bn[nrow*64 + m] = acc;
  }
}

// Wn[n][k][i][o] = sum_d Eg[n,d] * W_pool[d,k,i,o]   (stored bf16)
__global__ __launch_bounds__(256) void k_Wn(char* __restrict__ wsb) {
  const float* F = (const float*)(wsb + CW_OFF);
  ushort_t* Wn = (ushort_t*)(wsb + WN_OFF);
  int idx = blockIdx.x*256 + threadIdx.x;   // < 2097152
  int o = idx & 63;
  int i = (idx >> 6) & 63;
  int k = (idx >> 12) & 1;
  int n = idx >> 13;
  float acc = 0.f;
  #pragma unroll
  for (int d = 0; d < 10; ++d)
    acc += F[F_EG + n*10 + d] * F[F_WPOOL + ((d*2 + k)*64 + i)*64 + o];
  Wn[idx] = (ushort_t)f2bf(acc);
}

// h0,z0; out t=0 (fp32); x_0 = relu(z0@Wg_in+bg_in) -> XB buf0
__global__ __launch_bounds__(512) void k_init2(char* __restrict__ wsb, float* __restrict__ out) {
  const float* F = (const float*)(wsb + CW_OFF);
  float* H = (float*)(wsb + H_OFF);
  float* Z = (float*)(wsb + Z_OFF);
  ushort_t* X0 = (ushort_t*)(wsb + XB_OFF);   // buffer 0

  const int tid = threadIdx.x;
  const int lr  = tid >> 4;
  const int o0  = (tid & 15) * 4;
  const int row = blockIdx.x * 32 + lr;

  __shared__ __align__(16) float sIn[32][68];

  float a0 = F[F_X0 + row*2 + 0];
  float a1 = F[F_X0 + row*2 + 1];
  float h[4], z[4];
  #pragma unroll
  for (int j = 0; j < 4; ++j) {
    h[j] = a0*F[F_WH + o0+j] + a1*F[F_WH + 64+o0+j] + F[F_BH + o0+j];
    z[j] = a0*F[F_WZ + o0+j] + a1*F[F_WZ + 64+o0+j] + F[F_BZ + o0+j];
  }
  *(float4*)(H + row*64 + o0) = make_float4(h[0],h[1],h[2],h[3]);
  *(float4*)(Z + row*64 + o0) = make_float4(z[0],z[1],z[2],z[3]);
  ntst4(out + (row*13)*64 + o0, z[0],z[1],z[2],z[3]);

  *(float4*)&sIn[lr][o0] = make_float4(z[0],z[1],z[2],z[3]);
  __syncthreads();
  float xr[4];
  { float4 bv = *(const float4*)(F + F_BGIN + o0);
    xr[0]=bv.x; xr[1]=bv.y; xr[2]=bv.z; xr[3]=bv.w; }
  dotf_4(&sIn[lr][0], F + F_WGIN, o0, xr);
  #pragma unroll
  for (int j=0;j<4;++j) xr[j] = fmaxf(xr[j], 0.f);
  { uint2 pk;
    pk.x = f2bf(xr[0]) | (f2bf(xr[1]) << 16);
    pk.y = f2bf(xr[2]) | (f2bf(xr[3]) << 16);
    *(uint2*)(X0 + row*64 + o0) = pk; }
}

// ---------------------------------------------------------------------------
// One vector-field stage — merged-epoch schedule (7 barriers, dual-stream
// epochs). Same decomposition/grid as the champion; f-path and g-path are
// independent until dh/dz, so each merged epoch carries both streams for ILP.
// ---------------------------------------------------------------------------
__global__ __launch_bounds__(512) void k_stage(
    const void* __restrict__ times,
    const void* __restrict__ cbv, const void* __restrict__ ccv, const void* __restrict__ cdv,
    char* __restrict__ wsb, float* __restrict__ out, int vfc)
{
  const float* F  = (const float*)(wsb + CW_OFF);
  const float* Aw = (const float*)(wsb + A_OFF);
  const float* bn = (const float*)(wsb + BN_OFF);
  const ushort_t* Wn = (const ushort_t*)(wsb + WN_OFF);
  ushort_t* XB = (ushort_t*)(wsb + XB_OFF);
  float* H   = (float*)(wsb + H_OFF);
  float* Z   = (float*)(wsb + Z_OFF);
  float* K1h = (float*)(wsb + K1H_OFF);
  float* K1z = (float*)(wsb + K1Z_OFF);
  float* K2h = (float*)(wsb + K2H_OFF);
  float* K2z = (float*)(wsb + K2Z_OFF);
  float* UH  = (float*)(wsb + UH_OFF);
  const bool f32in = inputs_are_f32(times);

  const int s  = vfc >> 2;
  const int st = vfc & 3;
  const ushort_t* Xc = XB + (vfc & 1) * 524288;
  ushort_t*       Xn = XB + ((vfc + 1) & 1) * 524288;

  const int tid = threadIdx.x;
  const int lr  = tid >> 4;
  const int o0  = (tid & 15) * 4;
  const int co0 = o0 * 2;
  const int bb  = blockIdx.x >> 3;
  const int nr  = blockIdx.x & 7;
  const int n   = nr * 32 + lr;
  const int row = bb * 256 + n;

  __shared__ __align__(16) float sIn[32][68];
  __shared__ __align__(16) float sT [32][68];
  __shared__ __align__(16) float sX [32][68];
  __shared__ __align__(16) float sUH[32][68];
  __shared__ __align__(16) float xs [128][68];

  // ---- A: own x row -> sX ; uh -> sUH ; stage xs half 0 -------------------
  { uint2 w = *(const uint2*)(Xc + row*64 + o0);
    *(float4*)&sX[lr][o0] = make_float4(bfl(w.x), bfh(w.x), bfl(w.y), bfh(w.y)); }
  { const float* UHsrc = (st == 0) ? H : UH;
    *(float4*)&sUH[lr][o0] = *(const float4*)(UHsrc + row*64 + o0); }
  #pragma unroll
  for (int q = tid; q < 2048; q += 512) {
    int r = q >> 4, c4 = q & 15;
    uint2 w = *(const uint2*)(Xc + (bb*256 + r)*64 + c4*4);
    *(float4*)&xs[r][c4*4] = make_float4(bfl(w.x), bfh(w.x), bfl(w.y), bfh(w.y));
  }
  __syncthreads();                                               // #1

  // ---- B: conv half 0  ||  f-L1 -------------------------------------------
  float y[4] = {0.f,0.f,0.f,0.f};
  const float* Arow = Aw + n*256;
  #pragma unroll 4
  for (int m4 = 0; m4 < 32; ++m4) {
    float4 av = *(const float4*)(Arow + m4*4);
    float am[4] = {av.x, av.y, av.z, av.w};
    #pragma unroll
    for (int mm = 0; mm < 4; ++mm) {
      float4 xv = *(const float4*)&xs[m4*4+mm][o0];
      y[0] += am[mm]*xv.x; y[1] += am[mm]*xv.y;
      y[2] += am[mm]*xv.z; y[3] += am[mm]*xv.w;
    }
  }
  float a1v[4];
  { float4 bv = *(const float4*)(F + F_BFIN + o0);
    a1v[0]=bv.x; a1v[1]=bv.y; a1v[2]=bv.z; a1v[3]=bv.w; }
  dotf_4(&sUH[lr][0], F + F_WFIN, o0, a1v);
  #pragma unroll
  for (int j=0;j<4;++j) a1v[j] = fmaxf(a1v[j], 0.f);
  __syncthreads();                                               // #2

  // ---- C: stage xs half 1 ; a1v -> sT -------------------------------------
  #pragma unroll
  for (int q = tid; q < 2048; q += 512) {
    int r = q >> 4, c4 = q & 15;
    uint2 w = *(const uint2*)(Xc + (bb*256 + 128 + r)*64 + c4*4);
    *(float4*)&xs[r][c4*4] = make_float4(bfl(w.x), bfh(w.x), bfl(w.y), bfh(w.y));
  }
  *(float4*)&sT[lr][o0] = make_float4(a1v[0],a1v[1],a1v[2],a1v[3]);
  __syncthreads();                                               // #3

  // ---- D: conv half 1  ||  f-L2 -------------------------------------------
  #pragma unroll 4
  for (int m4 = 0; m4 < 32; ++m4) {
    float4 av = *(const float4*)(Arow + 128 + m4*4);
    float am[4] = {av.x, av.y, av.z, av.w};
    #pragma unroll
    for (int mm = 0; mm < 4; ++mm) {
      float4 xv = *(const float4*)&xs[m4*4+mm][o0];
      y[0] += am[mm]*xv.x; y[1] += am[mm]*xv.y;
      y[2] += am[mm]*xv.z; y[3] += am[mm]*xv.w;
    }
  }
  float a2v[4];
  { float4 bv = *(const float4*)(F + F_BFHID + o0);
    a2v[0]=bv.x; a2v[1]=bv.y; a2v[2]=bv.z; a2v[3]=bv.w; }
  dotf_4(&sT[lr][0], F + F_WFHID, o0, a2v);
  #pragma unroll
  for (int j=0;j<4;++j) a2v[j] = fmaxf(a2v[j], 0.f);
  __syncthreads();                                               // #4

  // ---- E: y -> sT ; a2v -> sIn --------------------------------------------
  *(float4*)&sT [lr][o0] = make_float4(y[0],y[1],y[2],y[3]);
  *(float4*)&sIn[lr][o0] = make_float4(a2v[0],a2v[1],a2v[2],a2v[3]);
  __syncthreads();                                               // #5

  // ---- F: Wn mix -> og  ||  f-L3 + dX -------------------------------------
  float og[4];
  { float4 bv = *(const float4*)(bn + n*64 + o0); og[0]=bv.x; og[1]=bv.y; og[2]=bv.z; og[3]=bv.w; }
  const ushort_t* W0 = Wn + n*8192;
  #pragma unroll
  for (int i4 = 0; i4 < 16; ++i4) {
    float4 xa = *(const float4*)&sX[lr][i4*4];
    float4 ya = *(const float4*)&sT[lr][i4*4];
    float xav[4]={xa.x,xa.y,xa.z,xa.w};
    float yav[4]={ya.x,ya.y,ya.z,ya.w};
    #pragma unroll
    for (int ii = 0; ii < 4; ++ii) {
      int i = i4*4 + ii;
      uint2 w0 = *(const uint2*)(W0 + i*64 + o0);
      uint2 w1 = *(const uint2*)(W0 + 4096 + i*64 + o0);
      og[0] += xav[ii]*bfl(w0.x) + yav[ii]*bfl(w1.x);
      og[1] += xav[ii]*bfh(w0.x) + yav[ii]*bfh(w1.x);
      og[2] += xav[ii]*bfl(w0.y) + yav[ii]*bfl(w1.y);
      og[3] += xav[ii]*bfh(w0.y) + yav[ii]*bfh(w1.y);
    }
  }
  float fo[8];
  { float4 b0 = *(const float4*)(F + F_BFOUT + co0);
    float4 b1 = *(const float4*)(F + F_BFOUT + co0 + 4);
    fo[0]=b0.x; fo[1]=b0.y; fo[2]=b0.z; fo[3]=b0.w;
    fo[4]=b1.x; fo[5]=b1.y; fo[6]=b1.z; fo[7]=b1.w; }
  dotf_8(&sIn[lr][0], F + F_WFOUT, co0, fo);
  float f0[4], f1[4];
  #pragma unroll
  for (int j=0;j<4;++j){ f0[j]=fast_tanh(fo[2*j]); f1[j]=fast_tanh(fo[2*j+1]); }

  int sidx; float frac;
  if (st == 0)      { sidx = s; frac = 0.f; }
  else if (st == 1) { sidx = s; frac = 0.33333334f; }
  else if (st == 2) { sidx = s; frac = 0.66666669f; }
  else              { sidx = (s < 11) ? s+1 : 11; frac = (s < 11) ? 0.f : 1.f; }
  float dX0, dX1;
  if (f32in) {
    float2 vb = *(const float2*)((const float*)cbv + (row*12 + sidx)*2);
    float2 vc = *(const float2*)((const float*)ccv + (row*12 + sidx)*2);
    float2 vd = *(const float2*)((const float*)cdv + (row*12 + sidx)*2);
    dX0 = vb.x + (vc.x + vd.x*frac)*frac;
    dX1 = vb.y + (vc.y + vd.y*frac)*frac;
  } else {
    uint_t vb = *(const uint_t*)((const ushort_t*)cbv + (row*12 + sidx)*2);
    uint_t vc = *(const uint_t*)((const ushort_t*)ccv + (row*12 + sidx)*2);
    uint_t vd = *(const uint_t*)((const ushort_t*)cdv + (row*12 + sidx)*2);
    dX0 = bfl(vb) + (bfl(vc) + bfl(vd)*frac)*frac;
    dX1 = bfh(vb) + (bfh(vc) + bfh(vd)*frac)*frac;
  }
  *(float4*)&sUH[lr][o0] = make_float4(og[0],og[1],og[2],og[3]);   // og -> sUH
  __syncthreads();                                               // #6

  // ---- G: Wg_out -> g ; dh/dz ; RK state update ; uz -> sT ----------------
  float go[8];
  { float4 b0 = *(const float4*)(F + F_BGOUT + co0);
    float4 b1 = *(const float4*)(F + F_BGOUT + co0 + 4);
    go[0]=b0.x; go[1]=b0.y; go[2]=b0.z; go[3]=b0.w;
    go[4]=b1.x; go[5]=b1.y; go[6]=b1.z; go[7]=b1.w; }
  dotf_8(&sUH[lr][0], F + F_WGOUT, co0, go);
  float dh[4], dz[4];
  #pragma unroll
  for (int j=0;j<4;++j){
    float g0 = fast_tanh(go[2*j]);
    float g1 = fast_tanh(go[2*j+1]);
    float p0 = f0[j]*dX0, p1 = f1[j]*dX1;
    dh[j] = p0 + p1;
    dz[j] = g0*p0 + g1*p1;
  }

  float uh_n[4], uz_n[4];
  float4 hv = *(const float4*)(H + row*64 + o0);
  float4 zv = *(const float4*)(Z + row*64 + o0);
  float h[4] = {hv.x,hv.y,hv.z,hv.w};
  float z[4] = {zv.x,zv.y,zv.z,zv.w};

  if (st == 0) {
    *(float4*)(K1h + row*64 + o0) = make_float4(dh[0],dh[1],dh[2],dh[3]);
    *(float4*)(K1z + row*64 + o0) = make_float4(dz[0],dz[1],dz[2],dz[3]);
    #pragma unroll
    for (int j=0;j<4;++j){ uh_n[j]=h[j]+dh[j]*(1.f/3.f); uz_n[j]=z[j]+dz[j]*(1.f/3.f); }
  } else if (st == 1) {
    float4 k1hv = *(const float4*)(K1h + row*64 + o0);
    float4 k1zv = *(const float4*)(K1z + row*64 + o0);
    float k1hl[4]={k1hv.x,k1hv.y,k1hv.z,k1hv.w};
    float k1zl[4]={k1zv.x,k1zv.y,k1zv.z,k1zv.w};
    float Qh[4],Qz[4],Ph[4],Pz[4];
    #pragma unroll
    for (int j=0;j<4;++j){
      Qh[j]=k1hl[j]+3.f*dh[j]; Qz[j]=k1zl[j]+3.f*dz[j];
      Ph[j]=k1hl[j]-dh[j];     Pz[j]=k1zl[j]-dz[j];
      uh_n[j]=h[j]+dh[j]-k1hl[j]*(1.f/3.f);
      uz_n[j]=z[j]+dz[j]-k1zl[j]*(1.f/3.f);
    }
    *(float4*)(K1h + row*64 + o0) = make_float4(Qh[0],Qh[1],Qh[2],Qh[3]);
    *(float4*)(K1z + row*64 + o0) = make_float4(Qz[0],Qz[1],Qz[2],Qz[3]);
    *(float4*)(K2h + row*64 + o0) = make_float4(Ph[0],Ph[1],Ph[2],Ph[3]);
    *(float4*)(K2z + row*64 + o0) = make_float4(Pz[0],Pz[1],Pz[2],Pz[3]);
  } else if (st == 2) {
    float4 Qhv = *(const float4*)(K1h + row*64 + o0);
    float4 Qzv = *(const float4*)(K1z + row*64 + o0);
    float4 Phv = *(const float4*)(K2h + row*64 + o0);
    float4 Pzv = *(const float4*)(K2z + row*64 + o0);
    float Qh[4]={Qhv.x,Qhv.y,Qhv.z,Qhv.w}, Qz[4]={Qzv.x,Qzv.y,Qzv.z,Qzv.w};
    float Ph[4]={Phv.x,Phv.y,Phv.z,Phv.w}, Pz[4]={Pzv.x,Pzv.y,Pzv.z,Pzv.w};
    float Ah[4],Az[4];
    #pragma unroll
    for (int j=0;j<4;++j){
      Ah[j]=Qh[j]+3.f*dh[j]; Az[j]=Qz[j]+3.f*dz[j];   // k1+3k2+3k3
      uh_n[j]=h[j]+Ph[j]+dh[j];                        // h + k1-k2+k3
      uz_n[j]=z[j]+Pz[j]+dz[j];
    }
    *(float4*)(K1h + row*64 + o0) = make_float4(Ah[0],Ah[1],Ah[2],Ah[3]);
    *(float4*)(K1z + row*64 + o0) = make_float4(Az[0],Az[1],Az[2],Az[3]);
  } else {
    float4 Ahv = *(const float4*)(K1h + row*64 + o0);
    float4 Azv = *(const float4*)(K1z + row*64 + o0);
    #pragma unroll
    for (int j=0;j<4;++j){
      float hn = h[j] + 0.125f*(((const float*)&Ahv)[j] + dh[j]);
      float zn = z[j] + 0.125f*(((const float*)&Azv)[j] + dz[j]);
      uh_n[j]=hn; uz_n[j]=zn;
    }
    *(float4*)(H + row*64 + o0) = make_float4(uh_n[0],uh_n[1],uh_n[2],uh_n[3]);
    *(float4*)(Z + row*64 + o0) = make_float4(uz_n[0],uz_n[1],uz_n[2],uz_n[3]);
    ntst4(out + (row*13 + s + 1)*64 + o0, uz_n[0],uz_n[1],uz_n[2],uz_n[3]);
  }

  if (vfc < 47) {
    *(float4*)(UH + row*64 + o0) = make_float4(uh_n[0],uh_n[1],uh_n[2],uh_n[3]);
    *(float4*)&sT[lr][o0] = make_float4(uz_n[0],uz_n[1],uz_n[2],uz_n[3]);
    __syncthreads();                                             // #7

    // ---- H: x_{v+1} = relu(uz @ Wg_in + bg_in) ----------------------------
    float xr[4];
    { float4 bv = *(const float4*)(F + F_BGIN + o0);
      xr[0]=bv.x; xr[1]=bv.y; xr[2]=bv.z; xr[3]=bv.w; }
    dotf_4(&sT[lr][0], F + F_WGIN, o0, xr);
    #pragma unroll
    for (int j=0;j<4;++j) xr[j] = fmaxf(xr[j], 0.f);
    uint2 pk;
    pk.x = f2bf(xr[0]) | (f2bf(xr[1]) << 16);
    pk.y = f2bf(xr[2]) | (f2bf(xr[3]) << 16);
    *(uint2*)(Xn + row*64 + o0) = pk;
  }
}

extern "C" void kernel_launch(void* const* d_in, const int* in_sizes, int n_in,
                              void* d_out, int out_size, void* d_ws, size_t ws_size,
                              hipStream_t stream) {
  const void* times   = d_in[0];
  const void* coeff_a = d_in[1];
  const void* coeff_b = d_in[2];
  const void* coeff_c = d_in[3];
  const void* coeff_d = d_in[4];
  const void* W_h    = d_in[5];
  const void* b_h    = d_in[6];
  const void* W_z    = d_in[7];
  const void* b_z    = d_in[8];
  const void* Wf_in  = d_in[9];
  const void* bf_in  = d_in[10];
  const void* Wf_hid = d_in[11];
  const void* bf_hid = d_in[12];
  const void* Wf_out = d_in[13];
  const void* bf_out = d_in[14];
  const void* Wg_in  = d_in[15];
  const void* bg_in  = d_in[16];
  const void* Eg     = d_in[17];
  const void* W_pool = d_in[18];
  const void* b_pool = d_in[19];
  const void* Wg_out = d_in[20];
  const void* bg_out = d_in[21];

  char* wsb = (char*)d_ws;
  float* out = (float*)d_out;

  hipLaunchKernelGGL(k_conv, dim3(36), dim3(256), 0, stream,
                     times, coeff_a, W_h, b_h, W_z, b_z,
                     Wf_in, bf_in, Wf_hid, bf_hid, Wf_out, bf_out,
                     Wg_in, bg_in, Wg_out, bg_out, Eg, W_pool, b_pool, wsb);
  hipLaunchKernelGGL(k_A,    dim3(256),  dim3(256), 0, stream, wsb);
  hipLaunchKernelGGL(k_Wn,   dim3(8192), dim3(256), 0, stream, wsb);
  hipLaunchKernelGGL(k_init2, dim3(256), dim3(512), 0, stream, wsb, out);
  for (int vfc = 0; vfc < 48; ++vfc) {
    hipLaunchKernelGGL(k_stage, dim3(256), dim3(512), 0, stream,
                       times, coeff_b, coeff_c, coeff_d, wsb, out, vfc);
  }
}

// Round 12
// 4997.142 us; speedup vs baseline: 2.7715x; 2.7715x over previous
//
#include <hip/hip_runtime.h>

typedef unsigned short ushort_t;
typedef unsigned int uint_t;
typedef float f4v __attribute__((ext_vector_type(4)));

// Problem dims: B=32 N=256 T=13 CIN=2 HID=64 EMB=10 K=2
// Output: float32, (B,N,13,HID)
// ws layout (21,823,488 B footprint):
#define CW_OFF  0          // canonical fp32 inputs (524288 B)
#define A_OFF   524288     // A  fp32 256x256
#define BN_OFF  786432     // bn fp32 256x64
#define WN_OFF  851968     // Wn bf16 flat 256x2x64x64 (4 MB)
#define XB_OFF  5046272    // XB bf16 2 x (8192x64) x-exchange double buffer
#define H_OFF   7143424    // H  fp32 8192x64
#define Z_OFF   9240576    // Z  fp32 8192x64
#define K1H_OFF 11337728
#define K1Z_OFF 13434880
#define K2H_OFF 15532032
#define K2Z_OFF 17629184
#define UH_OFF  19726336

// float-element offsets inside canonical region F
#define F_X0     0
#define F_WH     16384
#define F_BH     16512
#define F_WZ     16576
#define F_BZ     16704
#define F_WFIN   16768
#define F_BFIN   20864
#define F_WFHID  20928
#define F_BFHID  25024
#define F_WFOUT  25088
#define F_BFOUT  33280
#define F_WGIN   33408
#define F_BGIN   37504
#define F_WGOUT  37568
#define F_BGOUT  45760
#define F_EG     45888
#define F_WPOOL  48448
#define F_BPOOL  130368

__device__ __forceinline__ float bfl(uint_t u){ union{uint_t i; float f;} c; c.i = u<<16; return c.f; }
__device__ __forceinline__ float bfh(uint_t u){ union{uint_t i; float f;} c; c.i = u & 0xffff0000u; return c.f; }
__device__ __forceinline__ float bf1(ushort_t u){ union{uint_t i; float f;} c; c.i = ((uint_t)u)<<16; return c.f; }
__device__ __forceinline__ uint_t f2bf(float x){
  uint_t u = __float_as_uint(x);
  uint_t r = u + 0x7fffu + ((u >> 16) & 1u);
  return r >> 16;
}
__device__ __forceinline__ float fast_tanh(float x){
  float e = __expf(2.0f*x);
  return 1.0f - 2.0f/(e+1.0f);
}
// input dtype probe: times = arange(T). bf16 -> word0 = 0x3F800000; f32 -> 0
__device__ __forceinline__ bool inputs_are_f32(const void* times){
  return ((const uint_t*)times)[0] != 0x3F800000u;
}
__device__ __forceinline__ void ntst4(float* p, float a, float b, float c, float d){
  f4v v; v[0]=a; v[1]=b; v[2]=c; v[3]=d;
  __builtin_nontemporal_store(v, (f4v*)p);
}

// acc[0..3] += sum_i act[i] * W[i*64 + o0 + j]   (W fp32, row stride 64)
__device__ __forceinline__ void dotf_4(const float* act, const float* W, int o0, float acc[4]) {
  const float4* a4 = (const float4*)act;
  #pragma unroll
  for (int i4 = 0; i4 < 16; ++i4) {
    float4 av4 = a4[i4];
    float av[4] = {av4.x, av4.y, av4.z, av4.w};
    #pragma unroll
    for (int ii = 0; ii < 4; ++ii) {
      float4 w = *(const float4*)(W + (i4*4+ii)*64 + o0);
      acc[0] += av[ii]*w.x; acc[1] += av[ii]*w.y;
      acc[2] += av[ii]*w.z; acc[3] += av[ii]*w.w;
    }
  }
}

// acc[0..7] += sum_i act[i] * W[i*128 + co0 + j]  (W fp32, row stride 128)
__device__ __forceinline__ void dotf_8(const float* act, const float* W, int co0, float acc[8]) {
  const float4* a4 = (const float4*)act;
  #pragma unroll
  for (int i4 = 0; i4 < 16; ++i4) {
    float4 av4 = a4[i4];
    float av[4] = {av4.x, av4.y, av4.z, av4.w};
    #pragma unroll
    for (int ii = 0; ii < 4; ++ii) {
      const float* wp = W + (i4*4+ii)*128 + co0;
      float4 w0 = *(const float4*)(wp);
      float4 w1 = *(const float4*)(wp + 4);
      float a = av[ii];
      acc[0] += a*w0.x; acc[1] += a*w0.y; acc[2] += a*w0.z; acc[3] += a*w0.w;
      acc[4] += a*w1.x; acc[5] += a*w1.y; acc[6] += a*w1.z; acc[7] += a*w1.w;
    }
  }
}

__device__ __forceinline__ void cvt_copy(float* dst, const void* src, int cnt, bool f32in){
  if (f32in) {
    const float* s = (const float*)src;
    for (int i = threadIdx.x; i < cnt; i += 256) dst[i] = s[i];
  } else {
    const ushort_t* s = (const ushort_t*)src;
    for (int i = threadIdx.x; i < cnt; i += 256) dst[i] = bf1(s[i]);
  }
}

// canonicalize weights + x0 slice to fp32 in ws (bf16 OR f32 inputs)
// grid 36: bid 0..3 x0 quarters; 4..19 W_pool chunks; 20..35 small tensors
__global__ __launch_bounds__(256) void k_conv(
    const void* times, const void* ca,
    const void* W_h, const void* b_h, const void* W_z, const void* b_z,
    const void* Wf_in, const void* bf_in, const void* Wf_hid, const void* bf_hid,
    const void* Wf_out, const void* bf_out, const void* Wg_in, const void* bg_in,
    const void* Wg_out, const void* bg_out, const void* Eg, const void* W_pool,
    const void* b_pool, char* __restrict__ wsb)
{
  const bool f32in = inputs_are_f32(times);
  float* F = (float*)(wsb + CW_OFF);
  const int bid = blockIdx.x;
  if (bid < 4) {                       // x0 gather: coeff_a[..., 0, :]
    const int base = bid * 4096;
    if (f32in) {
      const float* s = (const float*)ca;
      for (int i = threadIdx.x; i < 4096; i += 256) {
        int g = base + i;
        F[F_X0 + g] = s[(g >> 1)*24 + (g & 1)];
      }
    } else {
      const ushort_t* s = (const ushort_t*)ca;
      for (int i = threadIdx.x; i < 4096; i += 256) {
        int g = base + i;
        F[F_X0 + g] = bf1(s[(g >> 1)*24 + (g & 1)]);
      }
    }
    return;
  }
  if (bid < 20) {                      // W_pool chunk
    const int off = (bid - 4) * 5120;
    const void* srcp = f32in ? (const void*)((const float*)W_pool + off)
                             : (const void*)((const ushort_t*)W_pool + off);
    cvt_copy(F + F_WPOOL + off, srcp, 5120, f32in);
    return;
  }
  const void* src = nullptr; int dst = 0, cnt = 0;
  switch (bid) {
    case 20: src = W_h;    dst = F_WH;    cnt = 128;  break;
    case 21: src = b_h;    dst = F_BH;    cnt = 64;   break;
    case 22: src = W_z;    dst = F_WZ;    cnt = 128;  break;
    case 23: src = b_z;    dst = F_BZ;    cnt = 64;   break;
    case 24: src = Wf_in;  dst = F_WFIN;  cnt = 4096; break;
    case 25: src = bf_in;  dst = F_BFIN;  cnt = 64;   break;
    case 26: src = Wf_hid; dst = F_WFHID; cnt = 4096; break;
    case 27: src = bf_hid; dst = F_BFHID; cnt = 64;   break;
    case 28: src = Wf_out; dst = F_WFOUT; cnt = 8192; break;
    case 29: src = bf_out; dst = F_BFOUT; cnt = 128;  break;
    case 30: src = Wg_in;  dst = F_WGIN;  cnt = 4096; break;
    case 31: src = bg_in;  dst = F_BGIN;  cnt = 64;   break;
    case 32: src = Wg_out; dst = F_WGOUT; cnt = 8192; break;
    case 33: src = bg_out; dst = F_BGOUT; cnt = 128;  break;
    case 34: src = Eg;     dst = F_EG;    cnt = 2560; break;
    default: src = b_pool; dst = F_BPOOL; cnt = 640;  break;
  }
  cvt_copy(F + dst, src, cnt, f32in);
}

// A = softmax(relu(Eg @ Eg^T), axis=1) ; bn = Eg @ b_pool
__global__ __launch_bounds__(256) void k_A(char* __restrict__ wsb) {
  const float* F = (const float*)(wsb + CW_OFF);
  float* Aw = (float*)(wsb + A_OFF);
  float* bn = (float*)(wsb + BN_OFF);
  const int nrow = blockIdx.x;
  const int m = threadIdx.x;
  float eg_n[10];
  #pragma unroll
  for (int d = 0; d < 10; ++d) eg_n[d] = F[F_EG + nrow*10 + d];
  float dot = 0.f;
  #pragma unroll
  for (int d = 0; d < 10; ++d) dot += eg_n[d] * F[F_EG + m*10 + d];
  float v = fmaxf(dot, 0.f);
  __shared__ float red[256];
  red[m] = v; __syncthreads();
  for (int off = 128; off > 0; off >>= 1) {
    if (m < off) red[m] = fmaxf(red[m], red[m+off]);
    __syncthreads();
  }
  float vmax = red[0]; __syncthreads();
  float e = __expf(v - vmax);
  red[m] = e; __syncthreads();
  for (int off = 128; off > 0; off >>= 1) {
    if (m < off) red[m] += red[m+off];
    __syncthreads();
  }
  float ssum = red[0];
  Aw[nrow*256 + m] = e / ssum;
  if (m < 64) {
    float acc = 0.f;
    #pragma unroll
    for (int d = 0; d < 10; ++d) acc += eg_n[d] * F[F_BPOOL + d*64 + m];
    bn[nrow*64 + m] = acc;
  }
}

// Wn[n][k][i][o] = sum_d Eg[n,d] * W_pool[d,k,i,o]   (stored bf16)
__global__ __launch_bounds__(256) void k_Wn(char* __restrict__ wsb) {
  const float* F = (const float*)(wsb + CW_OFF);
  ushort_t* Wn = (ushort_t*)(wsb + WN_OFF);
  int idx = blockIdx.x*256 + threadIdx.x;   // < 2097152
  int o = idx & 63;
  int i = (idx >> 6) & 63;
  int k = (idx >> 12) & 1;
  int n = idx >> 13;
  float acc = 0.f;
  #pragma unroll
  for (int d = 0; d < 10; ++d)
    acc += F[F_EG + n*10 + d] * F[F_WPOOL + ((d*2 + k)*64 + i)*64 + o];
  Wn[idx] = (ushort_t)f2bf(acc);
}

// h0,z0; out t=0 (fp32); x_0 = relu(z0@Wg_in+bg_in) -> XB buf0
__global__ __launch_bounds__(512) void k_init2(char* __restrict__ wsb, float* __restrict__ out) {
  const float* F = (const float*)(wsb + CW_OFF);
  float* H = (float*)(wsb + H_OFF);
  float* Z = (float*)(wsb + Z_OFF);
  ushort_t* X0 = (ushort_t*)(wsb + XB_OFF);   // buffer 0

  const int tid = threadIdx.x;
  const int lr  = tid >> 4;
  const int o0  = (tid & 15) * 4;
  const int row = blockIdx.x * 32 + lr;

  __shared__ __align__(16) float sIn[32][68];

  float a0 = F[F_X0 + row*2 + 0];
  float a1 = F[F_X0 + row*2 + 1];
  float h[4], z[4];
  #pragma unroll
  for (int j = 0; j < 4; ++j) {
    h[j] = a0*F[F_WH + o0+j] + a1*F[F_WH + 64+o0+j] + F[F_BH + o0+j];
    z[j] = a0*F[F_WZ + o0+j] + a1*F[F_WZ + 64+o0+j] + F[F_BZ + o0+j];
  }
  *(float4*)(H + row*64 + o0) = make_float4(h[0],h[1],h[2],h[3]);
  *(float4*)(Z + row*64 + o0) = make_float4(z[0],z[1],z[2],z[3]);
  ntst4(out + (row*13)*64 + o0, z[0],z[1],z[2],z[3]);

  *(float4*)&sIn[lr][o0] = make_float4(z[0],z[1],z[2],z[3]);
  __syncthreads();
  float xr[4];
  { float4 bv = *(const float4*)(F + F_BGIN + o0);
    xr[0]=bv.x; xr[1]=bv.y; xr[2]=bv.z; xr[3]=bv.w; }
  dotf_4(&sIn[lr][0], F + F_WGIN, o0, xr);
  #pragma unroll
  for (int j=0;j<4;++j) xr[j] = fmaxf(xr[j], 0.f);
  { uint2 pk;
    pk.x = f2bf(xr[0]) | (f2bf(xr[1]) << 16);
    pk.y = f2bf(xr[2]) | (f2bf(xr[3]) << 16);
    *(uint2*)(X0 + row*64 + o0) = pk; }
}

// one vector-field stage: conv(x_v) -> g ; f(uh_v) ; dX ; state update ; x_{v+1}
__global__ __launch_bounds__(512) void k_stage(
    const void* __restrict__ times,
    const void* __restrict__ cbv, const void* __restrict__ ccv, const void* __restrict__ cdv,
    char* __restrict__ wsb, float* __restrict__ out, int vfc)
{
  const float* F  = (const float*)(wsb + CW_OFF);
  const float* Aw = (const float*)(wsb + A_OFF);
  const float* bn = (const float*)(wsb + BN_OFF);
  const ushort_t* Wn = (const ushort_t*)(wsb + WN_OFF);
  ushort_t* XB = (ushort_t*)(wsb + XB_OFF);
  float* H   = (float*)(wsb + H_OFF);
  float* Z   = (float*)(wsb + Z_OFF);
  float* K1h = (float*)(wsb + K1H_OFF);
  float* K1z = (float*)(wsb + K1Z_OFF);
  float* K2h = (float*)(wsb + K2H_OFF);
  float* K2z = (float*)(wsb + K2Z_OFF);
  float* UH  = (float*)(wsb + UH_OFF);
  const bool f32in = inputs_are_f32(times);

  const int s  = vfc >> 2;
  const int st = vfc & 3;
  const ushort_t* Xc = XB + (vfc & 1) * 524288;
  ushort_t*       Xn = XB + ((vfc + 1) & 1) * 524288;

  const int tid = threadIdx.x;
  const int lr  = tid >> 4;
  const int o0  = (tid & 15) * 4;
  const int co0 = o0 * 2;
  const int bb  = blockIdx.x >> 3;
  const int nr  = blockIdx.x & 7;
  const int n   = nr * 32 + lr;
  const int row = bb * 256 + n;

  __shared__ __align__(16) float sIn[32][68];
  __shared__ __align__(16) float sT [32][68];
  __shared__ __align__(16) float sX [32][68];
  __shared__ __align__(16) float xs [128][68];

  // own x row
  { uint2 w = *(const uint2*)(Xc + row*64 + o0);
    *(float4*)&sX[lr][o0] = make_float4(bfl(w.x), bfh(w.x), bfl(w.y), bfh(w.y)); }

  // graph conv: y[n] = A[n,:] @ x[bb,:,:]   (two 128-row halves through LDS)
  float y[4] = {0.f,0.f,0.f,0.f};
  const float* Arow = Aw + n*256;
  #pragma unroll 1
  for (int half = 0; half < 2; ++half) {
    __syncthreads();
    #pragma unroll
    for (int q = tid; q < 2048; q += 512) {
      int r = q >> 4, c4 = q & 15;
      uint2 w = *(const uint2*)(Xc + (bb*256 + half*128 + r)*64 + c4*4);
      *(float4*)&xs[r][c4*4] = make_float4(bfl(w.x), bfh(w.x), bfl(w.y), bfh(w.y));
    }
    __syncthreads();
    #pragma unroll 4
    for (int m4 = 0; m4 < 32; ++m4) {
      float4 av = *(const float4*)(Arow + half*128 + m4*4);
      float am[4] = {av.x, av.y, av.z, av.w};
      #pragma unroll
      for (int mm = 0; mm < 4; ++mm) {
        float4 xv = *(const float4*)&xs[m4*4+mm][o0];
        y[0] += am[mm]*xv.x; y[1] += am[mm]*xv.y;
        y[2] += am[mm]*xv.z; y[3] += am[mm]*xv.w;
      }
    }
  }

  // og = bn[n] + x@Wn[n,0] + y@Wn[n,1]
  __syncthreads();
  *(float4*)&sT[lr][o0] = make_float4(y[0],y[1],y[2],y[3]);
  __syncthreads();
  float og[4];
  { float4 bv = *(const float4*)(bn + n*64 + o0); og[0]=bv.x; og[1]=bv.y; og[2]=bv.z; og[3]=bv.w; }
  const ushort_t* W0 = Wn + n*8192;
  #pragma unroll
  for (int i4 = 0; i4 < 16; ++i4) {
    float4 xa = *(const float4*)&sX[lr][i4*4];
    float4 ya = *(const float4*)&sT[lr][i4*4];
    float xav[4]={xa.x,xa.y,xa.z,xa.w};
    float yav[4]={ya.x,ya.y,ya.z,ya.w};
    #pragma unroll
    for (int ii = 0; ii < 4; ++ii) {
      int i = i4*4 + ii;
      uint2 w0 = *(const uint2*)(W0 + i*64 + o0);
      uint2 w1 = *(const uint2*)(W0 + 4096 + i*64 + o0);
      og[0] += xav[ii]*bfl(w0.x) + yav[ii]*bfl(w1.x);
      og[1] += xav[ii]*bfh(w0.x) + yav[ii]*bfh(w1.x);
      og[2] += xav[ii]*bfl(w0.y) + yav[ii]*bfl(w1.y);
      og[3] += xav[ii]*bfh(w0.y) + yav[ii]*bfh(w1.y);
    }
  }
  *(float4*)&sIn[lr][o0] = make_float4(og[0],og[1],og[2],og[3]);
  __syncthreads();
  float go[8];
  { float4 b0 = *(const float4*)(F + F_BGOUT + co0);
    float4 b1 = *(const float4*)(F + F_BGOUT + co0 + 4);
    go[0]=b0.x; go[1]=b0.y; go[2]=b0.z; go[3]=b0.w;
    go[4]=b1.x; go[5]=b1.y; go[6]=b1.z; go[7]=b1.w; }
  dotf_8(&sIn[lr][0], F + F_WGOUT, co0, go);
  float g0[4], g1[4];
  #pragma unroll
  for (int j=0;j<4;++j){ g0[j]=fast_tanh(go[2*j]); g1[j]=fast_tanh(go[2*j+1]); }

  // f-path from uh_v (st=0: uh = h)
  __syncthreads();                       // dotf_8 reads of sIn done
  { const float* UHsrc = (st == 0) ? H : UH;
    float4 uv = *(const float4*)(UHsrc + row*64 + o0);
    *(float4*)&sIn[lr][o0] = uv; }
  __syncthreads();
  float a1v[4];
  { float4 bv = *(const float4*)(F + F_BFIN + o0);
    a1v[0]=bv.x; a1v[1]=bv.y; a1v[2]=bv.z; a1v[3]=bv.w; }
  dotf_4(&sIn[lr][0], F + F_WFIN, o0, a1v);
  #pragma unroll
  for (int j=0;j<4;++j) a1v[j] = fmaxf(a1v[j], 0.f);
  *(float4*)&sT[lr][o0] = make_float4(a1v[0],a1v[1],a1v[2],a1v[3]);
  __syncthreads();
  float a2v[4];
  { float4 bv = *(const float4*)(F + F_BFHID + o0);
    a2v[0]=bv.x; a2v[1]=bv.y; a2v[2]=bv.z; a2v[3]=bv.w; }
  dotf_4(&sT[lr][0], F + F_WFHID, o0, a2v);
  #pragma unroll
  for (int j=0;j<4;++j) a2v[j] = fmaxf(a2v[j], 0.f);
  *(float4*)&sIn[lr][o0] = make_float4(a2v[0],a2v[1],a2v[2],a2v[3]);
  __syncthreads();
  float fo[8];
  { float4 b0 = *(const float4*)(F + F_BFOUT + co0);
    float4 b1 = *(const float4*)(F + F_BFOUT + co0 + 4);
    fo[0]=b0.x; fo[1]=b0.y; fo[2]=b0.z; fo[3]=b0.w;
    fo[4]=b1.x; fo[5]=b1.y; fo[6]=b1.z; fo[7]=b1.w; }
  dotf_8(&sIn[lr][0], F + F_WFOUT, co0, fo);
  float f0[4], f1[4];
  #pragma unroll
  for (int j=0;j<4;++j){ f0[j]=fast_tanh(fo[2*j]); f1[j]=fast_tanh(fo[2*j+1]); }

  // dX at this stage's time
  int sidx; float frac;
  if (st == 0)      { sidx = s; frac = 0.f; }
  else if (st == 1) { sidx = s; frac = 0.33333334f; }
  else if (st == 2) { sidx = s; frac = 0.66666669f; }
  else              { sidx = (s < 11) ? s+1 : 11; frac = (s < 11) ? 0.f : 1.f; }
  float dX0, dX1;
  if (f32in) {
    float2 vb = *(const float2*)((const float*)cbv + (row*12 + sidx)*2);
    float2 vc = *(const float2*)((const float*)ccv + (row*12 + sidx)*2);
    float2 vd = *(const float2*)((const float*)cdv + (row*12 + sidx)*2);
    dX0 = vb.x + (vc.x + vd.x*frac)*frac;
    dX1 = vb.y + (vc.y + vd.y*frac)*frac;
  } else {
    uint_t vb = *(const uint_t*)((const ushort_t*)cbv + (row*12 + sidx)*2);
    uint_t vc = *(const uint_t*)((const ushort_t*)ccv + (row*12 + sidx)*2);
    uint_t vd = *(const uint_t*)((const ushort_t*)cdv + (row*12 + sidx)*2);
    dX0 = bfl(vb) + (bfl(vc) + bfl(vd)*frac)*frac;
    dX1 = bfh(vb) + (bfh(vc) + bfh(vd)*frac)*frac;
  }

  float dh[4], dz[4];
  #pragma unroll
  for (int j=0;j<4;++j){
    dh[j] = f0[j]*dX0 + f1[j]*dX1;
    dz[j] = g0[j]*f0[j]*dX0 + g1[j]*f1[j]*dX1;
  }

  // state update
  float uh_n[4], uz_n[4];
  float4 hv = *(const float4*)(H + row*64 + o0);
  float4 zv = *(const float4*)(Z + row*64 + o0);
  float h[4] = {hv.x,hv.y,hv.z,hv.w};
  float z[4] = {zv.x,zv.y,zv.z,zv.w};

  if (st == 0) {
    *(float4*)(K1h + row*64 + o0) = make_float4(dh[0],dh[1],dh[2],dh[3]);
    *(float4*)(K1z + row*64 + o0) = make_float4(dz[0],dz[1],dz[2],dz[3]);
    #pragma unroll
    for (int j=0;j<4;++j){ uh_n[j]=h[j]+dh[j]*(1.f/3.f); uz_n[j]=z[j]+dz[j]*(1.f/3.f); }
  } else if (st == 1) {
    float4 k1hv = *(const float4*)(K1h + row*64 + o0);
    float4 k1zv = *(const float4*)(K1z + row*64 + o0);
    float k1hl[4]={k1hv.x,k1hv.y,k1hv.z,k1hv.w};
    float k1zl[4]={k1zv.x,k1zv.y,k1zv.z,k1zv.w};
    float Qh[4],Qz[4],Ph[4],Pz[4];
    #pragma unroll
    for (int j=0;j<4;++j){
      Qh[j]=k1hl[j]+3.f*dh[j]; Qz[j]=k1zl[j]+3.f*dz[j];
      Ph[j]=k1hl[j]-dh[j];     Pz[j]=k1zl[j]-dz[j];
      uh_n[j]=h[j]+dh[j]-k1hl[j]*(1.f/3.f);
      uz_n[j]=z[j]+dz[j]-k1zl[j]*(1.f/3.f);
    }
    *(float4*)(K1h + row*64 + o0) = make_float4(Qh[0],Qh[1],Qh[2],Qh[3]);
    *(float4*)(K1z + row*64 + o0) = make_float4(Qz[0],Qz[1],Qz[2],Qz[3]);
    *(float4*)(K2h + row*64 + o0) = make_float4(Ph[0],Ph[1],Ph[2],Ph[3]);
    *(float4*)(K2z + row*64 + o0) = make_float4(Pz[0],Pz[1],Pz[2],Pz[3]);
  } else if (st == 2) {
    float4 Qhv = *(const float4*)(K1h + row*64 + o0);
    float4 Qzv = *(const float4*)(K1z + row*64 + o0);
    float4 Phv = *(const float4*)(K2h + row*64 + o0);
    float4 Pzv = *(const float4*)(K2z + row*64 + o0);
    float Qh[4]={Qhv.x,Qhv.y,Qhv.z,Qhv.w}, Qz[4]={Qzv.x,Qzv.y,Qzv.z,Qzv.w};
    float Ph[4]={Phv.x,Phv.y,Phv.z,Phv.w}, Pz[4]={Pzv.x,Pzv.y,Pzv.z,Pzv.w};
    float Ah[4],Az[4];
    #pragma unroll
    for (int j=0;j<4;++j){
      Ah[j]=Qh[j]+3.f*dh[j]; Az[j]=Qz[j]+3.f*dz[j];   // k1+3k2+3k3
      uh_n[j]=h[j]+Ph[j]+dh[j];                        // h + k1-k2+k3
      uz_n[j]=z[j]+Pz[j]+dz[j];
    }
    *(float4*)(K1h + row*64 + o0) = make_float4(Ah[0],Ah[1],Ah[2],Ah[3]);
    *(float4*)(K1z + row*64 + o0) = make_float4(Az[0],Az[1],Az[2],Az[3]);
  } else {
    float4 Ahv = *(const float4*)(K1h + row*64 + o0);
    float4 Azv = *(const float4*)(K1z + row*64 + o0);
    #pragma unroll
    for (int j=0;j<4;++j){
      float hn = h[j] + 0.125f*(((const float*)&Ahv)[j] + dh[j]);
      float zn = z[j] + 0.125f*(((const float*)&Azv)[j] + dz[j]);
      uh_n[j]=hn; uz_n[j]=zn;
    }
    *(float4*)(H + row*64 + o0) = make_float4(uh_n[0],uh_n[1],uh_n[2],uh_n[3]);
    *(float4*)(Z + row*64 + o0) = make_float4(uz_n[0],uz_n[1],uz_n[2],uz_n[3]);
    ntst4(out + (row*13 + s + 1)*64 + o0, uz_n[0],uz_n[1],uz_n[2],uz_n[3]);
  }

  if (vfc < 47) {
    *(float4*)(UH + row*64 + o0) = make_float4(uh_n[0],uh_n[1],uh_n[2],uh_n[3]);
    // x_{v+1} = relu(uz_n @ Wg_in + bg_in)
    __syncthreads();                     // dotf_8(fo) reads of sIn done
    *(float4*)&sIn[lr][o0] = make_float4(uz_n[0],uz_n[1],uz_n[2],uz_n[3]);
    __syncthreads();
    float xr[4];
    { float4 bv = *(const float4*)(F + F_BGIN + o0);
      xr[0]=bv.x; xr[1]=bv.y; xr[2]=bv.z; xr[3]=bv.w; }
    dotf_4(&sIn[lr][0], F + F_WGIN, o0, xr);
    #pragma unroll
    for (int j=0;j<4;++j) xr[j] = fmaxf(xr[j], 0.f);
    uint2 pk;
    pk.x = f2bf(xr[0]) | (f2bf(xr[1]) << 16);
    pk.y = f2bf(xr[2]) | (f2bf(xr[3]) << 16);
    *(uint2*)(Xn + row*64 + o0) = pk;
  }
}

extern "C" void kernel_launch(void* const* d_in, const int* in_sizes, int n_in,
                              void* d_out, int out_size, void* d_ws, size_t ws_size,
                              hipStream_t stream) {
  const void* times   = d_in[0];
  const void* coeff_a = d_in[1];
  const void* coeff_b = d_in[2];
  const void* coeff_c = d_in[3];
  const void* coeff_d = d_in[4];
  const void* W_h    = d_in[5];
  const void* b_h    = d_in[6];
  const void* W_z    = d_in[7];
  const void* b_z    = d_in[8];
  const void* Wf_in  = d_in[9];
  const void* bf_in  = d_in[10];
  const void* Wf_hid = d_in[11];
  const void* bf_hid = d_in[12];
  const void* Wf_out = d_in[13];
  const void* bf_out = d_in[14];
  const void* Wg_in  = d_in[15];
  const void* bg_in  = d_in[16];
  const void* Eg     = d_in[17];
  const void* W_pool = d_in[18];
  const void* b_pool = d_in[19];
  const void* Wg_out = d_in[20];
  const void* bg_out = d_in[21];

  char* wsb = (char*)d_ws;
  float* out = (float*)d_out;

  hipLaunchKernelGGL(k_conv, dim3(36), dim3(256), 0, stream,
                     times, coeff_a, W_h, b_h, W_z, b_z,
                     Wf_in, bf_in, Wf_hid, bf_hid, Wf_out, bf_out,
                     Wg_in, bg_in, Wg_out, bg_out, Eg, W_pool, b_pool, wsb);
  hipLaunchKernelGGL(k_A,    dim3(256),  dim3(256), 0, stream, wsb);
  hipLaunchKernelGGL(k_Wn,   dim3(8192), dim3(256), 0, stream, wsb);
  hipLaunchKernelGGL(k_init2, dim3(256), dim3(512), 0, stream, wsb, out);
  for (int vfc = 0; vfc < 48; ++vfc) {
    hipLaunchKernelGGL(k_stage, dim3(256), dim3(512), 0, stream,
                       times, coeff_b, coeff_c, coeff_d, wsb, out, vfc);
  }
}